// Round 6
// baseline (662.396 us; speedup 1.0000x reference)
//
#include <hip/hip_runtime.h>

// VectorQuantizationLayer1D: N=262144 pts, D=64, K=1024 codewords.
// out (f32): [0,N) idx-as-float | [N,2N) dist | [2N,..) gathered codewords.
//
// Round 11: K-split persistent blocks, barrier-free main loop.
// R9/R10 proved the limiter is per-wave serial latency under the 2-blocks/CU
// barrier-per-chunk structure (stagger/setprio changed nothing; fewer blocks
// made it worse). New structure: 256 blocks x 1024 threads (16 waves = 4/SIMD,
// 2x occupancy). Block b owns K-half (b&1): stages its 144 KB half-image into
// LDS ONCE, then ZERO barriers: each wave self-paced over 2 point-tiles x 512
// codewords (split-bf16 3-pass MFMA, packed-tag fmin tracking - all proven).
// Top-2 per slot via min-butterfly + ballot/ffs winner-lane + exclude + second
// min (cheaper than full top-2 butterfly; exact smallest-index tie-breaks).
// Per-lane exact fp32 rescore of its own point's 2 candidates -> partial
// (idx,dist) per K-half written into the gather region of out (scratch):
//   [2N..3N) idx_h0 | [3N..4N) dist_h0 | [4N..5N) idx_h1 | [5N..6N) dist_h1
// vq_merge1 picks the winning half (reads scratch, writes idx/dist outputs);
// vq_merge2 gathers codeword rows (overwrites scratch; kernel boundary = sync).
// ws: 8 chunks x 36864 B, row = 72 shorts [hi bf16 x64 | c2 f32 | pad]; lo
// image at +9216 shorts. Total 294912 B (same proven footprint).

#define N_PTS 262144
#define K_CW  1024
#define DIM   64
#define CHUNK_B 36864            // bytes per 128-codeword chunk image
#define HALF_B  (4 * CHUNK_B)    // 147456 B = 512-codeword half image

typedef __attribute__((ext_vector_type(8)))  short short8;
typedef __attribute__((ext_vector_type(16))) float floatx16;

__device__ __forceinline__ unsigned short f2bf(float f) {
    unsigned u = __float_as_uint(f);
    return (unsigned short)((u + 0x7FFFu + ((u >> 16) & 1u)) >> 16);
}
__device__ __forceinline__ float bf2f(unsigned short h) {
    return __uint_as_float(((unsigned)h) << 16);
}
__device__ __forceinline__ float dot4(float4 a, float4 b) {
    return a.x*b.x + a.y*b.y + a.z*b.z + a.w*b.w;
}
__device__ __forceinline__ void async_cp16(const void* g, void* l) {
    __builtin_amdgcn_global_load_lds(
        (const __attribute__((address_space(1))) unsigned int*)g,
        (__attribute__((address_space(3))) unsigned int*)l, 16, 0, 0);
}

// ---- prep: split (-2*codebook) into bf16 hi/lo LDS-image; c2 in row pad ----
__global__ void vq_prep(const float* __restrict__ cw, unsigned char* __restrict__ ws) {
    const int k = blockIdx.x * 256 + threadIdx.x;   // codeword 0..1023
    const int ch = k >> 7, r = k & 127;
    unsigned short* chunk = (unsigned short*)(ws + (size_t)ch * CHUNK_B);
    unsigned short* hi = chunk + r * 72;
    unsigned short* lo = hi + 9216;
    const float4* cr = (const float4*)cw + (size_t)k * 16;
    float c2 = 0.f;
    #pragma unroll
    for (int j = 0; j < 16; ++j) {
        float4 v = cr[j];
        c2 += dot4(v, v);
        float4 m = make_float4(-2.f*v.x, -2.f*v.y, -2.f*v.z, -2.f*v.w);
        unsigned short h0 = f2bf(m.x), h1 = f2bf(m.y), h2 = f2bf(m.z), h3 = f2bf(m.w);
        unsigned short l0 = f2bf(m.x - bf2f(h0)), l1 = f2bf(m.y - bf2f(h1)),
                       l2 = f2bf(m.z - bf2f(h2)), l3 = f2bf(m.w - bf2f(h3));
        uint2 hv, lv;
        hv.x = (unsigned)h0 | ((unsigned)h1 << 16);
        hv.y = (unsigned)h2 | ((unsigned)h3 << 16);
        lv.x = (unsigned)l0 | ((unsigned)l1 << 16);
        lv.y = (unsigned)l2 | ((unsigned)l3 << 16);
        *(uint2*)(hi + j * 4) = hv;
        *(uint2*)(lo + j * 4) = lv;
    }
    *(float*)(hi + 64) = c2;    // row pad, byte 128..131 of the 144 B row
}

__launch_bounds__(1024)
__global__ void vq_main(const float* __restrict__ x,
                        const float* __restrict__ cw,
                        const unsigned char* __restrict__ ws,
                        float* __restrict__ out) {
    __shared__ __align__(16) unsigned char sB[HALF_B];   // 144 KB, staged once

    const int tid  = threadIdx.x;
    const int w    = tid >> 6;          // wave 0..15
    const int lane = tid & 63;
    const int q    = lane >> 5;
    const int l31  = lane & 31;
    const int half  = blockIdx.x & 1;          // K-half: codewords [half*512, +512)
    const int pbase = (blockIdx.x >> 1) * 2048;
    const float4* __restrict__ x4  = (const float4*)x;
    const float4* __restrict__ c4p = (const float4*)cw;

    // ---- stage this half's 144 KB image into LDS (once; linear copy) ----
    {
        const unsigned char* g = ws + (size_t)half * HALF_B + tid * 16;
        unsigned char* l = sB + tid * 16;
        #pragma unroll
        for (int s = 0; s < 9; ++s) async_cp16(g + s * 16384, l + s * 16384);
    }
    __syncthreads();   // only barrier in the kernel; LDS read-only afterwards

    const unsigned short* __restrict__ S = (const unsigned short*)sB;

    // ---- per-wave loop: 2 tiles of 64 points, fully self-paced ----
    for (int t = 0; t < 2; ++t) {
        const int tbase = pbase + w * 128 + t * 64;

        // A fragments from global (rows tbase + rt*32 + l31), split bf16
        short8 ah[2][4], al[2][4];
        #pragma unroll
        for (int rt = 0; rt < 2; ++rt) {
            const int row = tbase + rt * 32 + l31;
            const float4* xr = x4 + (size_t)row * 16;
            #pragma unroll
            for (int ks = 0; ks < 4; ++ks) {
                float4 va = xr[ks * 4 + q * 2];
                float4 vb = xr[ks * 4 + q * 2 + 1];
                float f[8] = {va.x, va.y, va.z, va.w, vb.x, vb.y, vb.z, vb.w};
                short8 h, l;
                #pragma unroll
                for (int j = 0; j < 8; ++j) {
                    unsigned short hb = f2bf(f[j]);
                    h[j] = (short)hb;
                    l[j] = (short)f2bf(f[j] - bf2f(hb));
                }
                ah[rt][ks] = h; al[rt][ks] = l;
            }
        }

        // packed candidates: (c2 - 2x.c) with low 5 mantissa bits = tag g
        float bu[32];
        #pragma unroll
        for (int s = 0; s < 32; ++s) bu[s] = 3.4e38f;

        #pragma unroll 4
        for (int g = 0; g < 16; ++g) {     // 16 col-tiles of 32 codewords
            const unsigned short* chS = S + (g >> 2) * (CHUNK_B / 2);
            const int nrow = (g & 3) * 32 + l31;
            short8 bh[4], bl[4];
            #pragma unroll
            for (int ks = 0; ks < 4; ++ks) {
                bh[ks] = *(const short8*)&chS[nrow * 72 + ks * 16 + q * 8];
                bl[ks] = *(const short8*)&chS[9216 + nrow * 72 + ks * 16 + q * 8];
            }
            const float c2v = *(const float*)&chS[nrow * 72 + 64];
            floatx16 a0, a1;
            #pragma unroll
            for (int r = 0; r < 16; ++r) { a0[r] = c2v; a1[r] = c2v; }
            __builtin_amdgcn_s_setprio(1);
            #pragma unroll
            for (int ks = 0; ks < 4; ++ks) {   // hh, lh, hl; 2 indep chains
                a0 = __builtin_amdgcn_mfma_f32_32x32x16_bf16(ah[0][ks], bh[ks], a0, 0, 0, 0);
                a1 = __builtin_amdgcn_mfma_f32_32x32x16_bf16(ah[1][ks], bh[ks], a1, 0, 0, 0);
                a0 = __builtin_amdgcn_mfma_f32_32x32x16_bf16(al[0][ks], bh[ks], a0, 0, 0, 0);
                a1 = __builtin_amdgcn_mfma_f32_32x32x16_bf16(al[1][ks], bh[ks], a1, 0, 0, 0);
                a0 = __builtin_amdgcn_mfma_f32_32x32x16_bf16(ah[0][ks], bl[ks], a0, 0, 0, 0);
                a1 = __builtin_amdgcn_mfma_f32_32x32x16_bf16(ah[1][ks], bl[ks], a1, 0, 0, 0);
            }
            __builtin_amdgcn_s_setprio(0);
            const unsigned tag = (unsigned)g;
            #pragma unroll
            for (int r = 0; r < 16; ++r) {
                unsigned u0 = (__float_as_uint(a0[r]) & 0xFFFFFFE0u) | tag;
                bu[r] = fminf(bu[r], __uint_as_float(u0));
                unsigned u1 = (__float_as_uint(a1[r]) & 0xFFFFFFE0u) | tag;
                bu[16 + r] = fminf(bu[16 + r], __uint_as_float(u1));
            }
        }

        // ---- top-2 per slot: min-butterfly + winner-lane exclude + min ----
        int keep_i0 = 0, keep_i1 = 0;
        #pragma unroll
        for (int s = 0; s < 32; ++s) {
            const float v = bu[s];
            float m1 = v;
            #pragma unroll
            for (int m = 1; m < 32; m <<= 1) m1 = fminf(m1, __shfl_xor(m1, m));
            unsigned long long bm = __ballot(v == m1);
            const int wl = __ffs((unsigned)(bm >> (q * 32))) - 1;   // smallest lane
            const float v2 = (l31 == wl) ? 3.4e38f : v;
            float m2 = v2;
            #pragma unroll
            for (int m = 1; m < 32; m <<= 1) m2 = fminf(m2, __shfl_xor(m2, m));
            unsigned long long bm2 = __ballot(v2 == m2);
            const int wl2 = __ffs((unsigned)(bm2 >> (q * 32))) - 1;
            const int i0 = (int)(((__float_as_uint(m1) & 31u) << 5) | (unsigned)wl);
            const int i1 = (int)(((__float_as_uint(m2) & 31u) << 5) | (unsigned)wl2);
            if (l31 == s) { keep_i0 = i0; keep_i1 = i1; }   // lane s owns slot s
        }

        // ---- per-lane exact fp32 rescore of its own point's 2 candidates ----
        const int rS   = l31 & 15;
        const int prow = (l31 >> 4) * 32 + (rS & 3) + 8 * (rS >> 2) + 4 * q;
        const int p    = tbase + prow;
        const int ia = keep_i0, ib = keep_i1;               // local [0,512)
        const float4* xr = x4 + (size_t)p * 16;
        const float4* ca = c4p + (size_t)(half * 512 + ia) * 16;
        const float4* cb = c4p + (size_t)(half * 512 + ib) * 16;
        float da = 0.f, db = 0.f;
        #pragma unroll
        for (int j = 0; j < 16; ++j) {
            float4 xv = xr[j], av = ca[j], bv = cb[j];
            float4 d1 = make_float4(xv.x-av.x, xv.y-av.y, xv.z-av.z, xv.w-av.w);
            float4 d2 = make_float4(xv.x-bv.x, xv.y-bv.y, xv.z-bv.z, xv.w-bv.w);
            da += dot4(d1, d1);
            db += dot4(d2, d2);
        }
        const bool ta = (da < db) || (da == db && ia < ib);
        const int   bidx = half * 512 + (ta ? ia : ib);
        const float bd   = ta ? da : db;
        // partial scratch in the gather region (overwritten later by merge2)
        float* Pi = out + (size_t)(2 + half * 2) * N_PTS;
        Pi[p]         = (float)bidx;
        Pi[N_PTS + p] = bd;
    }
}

// pick the winning half per point (reads scratch, writes idx+dist outputs)
__launch_bounds__(256)
__global__ void vq_merge1(float* __restrict__ out) {
    const int p = blockIdx.x * 256 + threadIdx.x;
    const float i0 = out[2 * (size_t)N_PTS + p];
    const float d0 = out[3 * (size_t)N_PTS + p];
    const float i1 = out[4 * (size_t)N_PTS + p];
    const float d1 = out[5 * (size_t)N_PTS + p];
    const bool ta = (d0 < d1) || (d0 == d1);   // tie -> half0 (smaller index)
    out[p]         = ta ? i0 : i1;
    out[N_PTS + p] = sqrtf(fmaxf(ta ? d0 : d1, 0.f));
}

// gather quantized_data (overwrites scratch; kernel boundary orders it)
__launch_bounds__(256)
__global__ void vq_merge2(const float* __restrict__ cw, float* __restrict__ out) {
    __shared__ int sidx[256];
    const int tid = threadIdx.x;
    const int base = blockIdx.x * 256;
    sidx[tid] = (int)out[base + tid];
    __syncthreads();
    const float4* c4p = (const float4*)cw;
    float4* od = (float4*)(out + 2 * (size_t)N_PTS) + (size_t)base * 16;
    #pragma unroll
    for (int i = 0; i < 16; ++i) {
        const int g = i * 256 + tid;
        od[g] = c4p[(size_t)sidx[g >> 4] * 16 + (g & 15)];
    }
}

extern "C" void kernel_launch(void* const* d_in, const int* in_sizes, int n_in,
                              void* d_out, int out_size, void* d_ws, size_t ws_size,
                              hipStream_t stream) {
    const float* x  = (const float*)d_in[0];
    const float* cw = (const float*)d_in[1];
    float* out = (float*)d_out;
    unsigned char* ws = (unsigned char*)d_ws;
    vq_prep<<<4, 256, 0, stream>>>(cw, ws);
    vq_main<<<256, 1024, 0, stream>>>(x, cw, ws, out);
    vq_merge1<<<N_PTS / 256, 256, 0, stream>>>(out);
    vq_merge2<<<N_PTS / 256, 256, 0, stream>>>(cw, out);
}

// Round 7
// 265.375 us; speedup vs baseline: 2.4961x; 2.4961x over previous
//
#include <hip/hip_runtime.h>

// VectorQuantizationLayer1D: N=262144 pts, D=64, K=1024 codewords.
// out (f32): [0,N) idx-as-float | [N,2N) dist | [2N,..) gathered codewords.
//
// Round 12: R11's K-split barrier-free structure, sized to the register file.
// R11 died of spills (VGPR_Count=64 at 1024 thr/block; ~180 needed; 2 GB of
// scratch traffic, MfmaUtil 8%). Fix: 512-thread blocks (8 waves) with
// __launch_bounds__(512,2) -> 256 VGPRs/wave budget, no spills. Block b owns
// K-half (b&1): stages its 144 KB half-image into LDS ONCE (single barrier),
// then each wave self-paced: 64 points x 512 codewords with the proven R6
// per-wave shape (split-bf16 3-pass MFMA, 2 indep chains, packed-tag fmin).
// vs R6: staging traffic halved, K-loop barriers eliminated (32 -> 4 per CU
// timeline), c2 from LDS row pad. Selection/merge numerics verbatim R11
// (passed at absmax 0.0625).
// Scratch in out[2N..6N): idx_h0 | dist_h0 | idx_h1 | dist_h1 (d2, pre-sqrt).
// vq_merge1 picks winning half; vq_merge2 gathers codeword rows (overwrites
// scratch; kernel boundary = device-wide sync).
// ws: 8 chunks x 36864 B, row = 72 shorts [hi bf16 x64 | c2 f32 | pad]; lo
// image at +9216 shorts. Total 294912 B.

#define N_PTS 262144
#define K_CW  1024
#define DIM   64
#define CHUNK_B 36864            // bytes per 128-codeword chunk image
#define HALF_B  (4 * CHUNK_B)    // 147456 B = 512-codeword half image

typedef __attribute__((ext_vector_type(8)))  short short8;
typedef __attribute__((ext_vector_type(16))) float floatx16;

__device__ __forceinline__ unsigned short f2bf(float f) {
    unsigned u = __float_as_uint(f);
    return (unsigned short)((u + 0x7FFFu + ((u >> 16) & 1u)) >> 16);
}
__device__ __forceinline__ float bf2f(unsigned short h) {
    return __uint_as_float(((unsigned)h) << 16);
}
__device__ __forceinline__ float dot4(float4 a, float4 b) {
    return a.x*b.x + a.y*b.y + a.z*b.z + a.w*b.w;
}
__device__ __forceinline__ void async_cp16(const void* g, void* l) {
    __builtin_amdgcn_global_load_lds(
        (const __attribute__((address_space(1))) unsigned int*)g,
        (__attribute__((address_space(3))) unsigned int*)l, 16, 0, 0);
}

// ---- prep: split (-2*codebook) into bf16 hi/lo LDS-image; c2 in row pad ----
__global__ void vq_prep(const float* __restrict__ cw, unsigned char* __restrict__ ws) {
    const int k = blockIdx.x * 256 + threadIdx.x;   // codeword 0..1023
    const int ch = k >> 7, r = k & 127;
    unsigned short* chunk = (unsigned short*)(ws + (size_t)ch * CHUNK_B);
    unsigned short* hi = chunk + r * 72;
    unsigned short* lo = hi + 9216;
    const float4* cr = (const float4*)cw + (size_t)k * 16;
    float c2 = 0.f;
    #pragma unroll
    for (int j = 0; j < 16; ++j) {
        float4 v = cr[j];
        c2 += dot4(v, v);
        float4 m = make_float4(-2.f*v.x, -2.f*v.y, -2.f*v.z, -2.f*v.w);
        unsigned short h0 = f2bf(m.x), h1 = f2bf(m.y), h2 = f2bf(m.z), h3 = f2bf(m.w);
        unsigned short l0 = f2bf(m.x - bf2f(h0)), l1 = f2bf(m.y - bf2f(h1)),
                       l2 = f2bf(m.z - bf2f(h2)), l3 = f2bf(m.w - bf2f(h3));
        uint2 hv, lv;
        hv.x = (unsigned)h0 | ((unsigned)h1 << 16);
        hv.y = (unsigned)h2 | ((unsigned)h3 << 16);
        lv.x = (unsigned)l0 | ((unsigned)l1 << 16);
        lv.y = (unsigned)l2 | ((unsigned)l3 << 16);
        *(uint2*)(hi + j * 4) = hv;
        *(uint2*)(lo + j * 4) = lv;
    }
    *(float*)(hi + 64) = c2;    // row pad, byte 128..131 of the 144 B row
}

__launch_bounds__(512, 2)
__global__ void vq_main(const float* __restrict__ x,
                        const float* __restrict__ cw,
                        const unsigned char* __restrict__ ws,
                        float* __restrict__ out) {
    __shared__ __align__(16) unsigned char sB[HALF_B];   // 144 KB, staged once

    const int tid  = threadIdx.x;
    const int w    = tid >> 6;          // wave 0..7
    const int lane = tid & 63;
    const int q    = lane >> 5;
    const int l31  = lane & 31;
    const int half  = blockIdx.x & 1;          // K-half: codewords [half*512, +512)
    const int pbase = (blockIdx.x >> 1) * 512;
    const float4* __restrict__ x4  = (const float4*)x;
    const float4* __restrict__ c4p = (const float4*)cw;

    // ---- stage this half's 144 KB image into LDS (once; linear copy) ----
    {
        const unsigned char* g = ws + (size_t)half * HALF_B + tid * 16;
        unsigned char* l = sB + tid * 16;
        #pragma unroll
        for (int s = 0; s < 18; ++s) async_cp16(g + s * 8192, l + s * 8192);
    }

    // ---- A fragments from global: wave w owns rows [w*64, w*64+64) ----
    short8 ah[2][4], al[2][4];
    #pragma unroll
    for (int rt = 0; rt < 2; ++rt) {
        const int row = pbase + w * 64 + rt * 32 + l31;
        const float4* xr = x4 + (size_t)row * 16;
        #pragma unroll
        for (int ks = 0; ks < 4; ++ks) {
            float4 va = xr[ks * 4 + q * 2];
            float4 vb = xr[ks * 4 + q * 2 + 1];
            float f[8] = {va.x, va.y, va.z, va.w, vb.x, vb.y, vb.z, vb.w};
            short8 h, l;
            #pragma unroll
            for (int j = 0; j < 8; ++j) {
                unsigned short hb = f2bf(f[j]);
                h[j] = (short)hb;
                l[j] = (short)f2bf(f[j] - bf2f(hb));
            }
            ah[rt][ks] = h; al[rt][ks] = l;
        }
    }

    __syncthreads();   // only barrier: image staged; LDS read-only afterwards

    const unsigned short* __restrict__ S = (const unsigned short*)sB;

    // packed candidates: (c2 - 2x.c) with low 5 mantissa bits = tag g
    float bu[32];
    #pragma unroll
    for (int s = 0; s < 32; ++s) bu[s] = 3.4e38f;

    #pragma unroll 4
    for (int g = 0; g < 16; ++g) {     // 16 col-tiles of 32 codewords
        const unsigned short* chS = S + (g >> 2) * (CHUNK_B / 2);
        const int nrow = (g & 3) * 32 + l31;
        short8 bh[4], bl[4];
        #pragma unroll
        for (int ks = 0; ks < 4; ++ks) {
            bh[ks] = *(const short8*)&chS[nrow * 72 + ks * 16 + q * 8];
            bl[ks] = *(const short8*)&chS[9216 + nrow * 72 + ks * 16 + q * 8];
        }
        const float c2v = *(const float*)&chS[nrow * 72 + 64];
        // acc starts at c2 (B is pre-scaled by -2): acc = c2 - 2 x.c
        floatx16 a0, a1;
        #pragma unroll
        for (int r = 0; r < 16; ++r) { a0[r] = c2v; a1[r] = c2v; }
        __builtin_amdgcn_s_setprio(1);
        #pragma unroll
        for (int ks = 0; ks < 4; ++ks) {   // hh, lh, hl; 2 indep chains
            a0 = __builtin_amdgcn_mfma_f32_32x32x16_bf16(ah[0][ks], bh[ks], a0, 0, 0, 0);
            a1 = __builtin_amdgcn_mfma_f32_32x32x16_bf16(ah[1][ks], bh[ks], a1, 0, 0, 0);
            a0 = __builtin_amdgcn_mfma_f32_32x32x16_bf16(al[0][ks], bh[ks], a0, 0, 0, 0);
            a1 = __builtin_amdgcn_mfma_f32_32x32x16_bf16(al[1][ks], bh[ks], a1, 0, 0, 0);
            a0 = __builtin_amdgcn_mfma_f32_32x32x16_bf16(ah[0][ks], bl[ks], a0, 0, 0, 0);
            a1 = __builtin_amdgcn_mfma_f32_32x32x16_bf16(ah[1][ks], bl[ks], a1, 0, 0, 0);
        }
        __builtin_amdgcn_s_setprio(0);
        const unsigned tag = (unsigned)g;
        #pragma unroll
        for (int r = 0; r < 16; ++r) {
            unsigned u0 = (__float_as_uint(a0[r]) & 0xFFFFFFE0u) | tag;
            bu[r] = fminf(bu[r], __uint_as_float(u0));
            unsigned u1 = (__float_as_uint(a1[r]) & 0xFFFFFFE0u) | tag;
            bu[16 + r] = fminf(bu[16 + r], __uint_as_float(u1));
        }
    }

    // ---- top-2 per slot: min-butterfly + winner-lane exclude + min ----
    int keep_i0 = 0, keep_i1 = 0;
    #pragma unroll
    for (int s = 0; s < 32; ++s) {
        const float v = bu[s];
        float m1 = v;
        #pragma unroll
        for (int m = 1; m < 32; m <<= 1) m1 = fminf(m1, __shfl_xor(m1, m));
        unsigned long long bm = __ballot(v == m1);
        const int wl = __ffs((unsigned)(bm >> (q * 32))) - 1;   // smallest lane
        const float v2 = (l31 == wl) ? 3.4e38f : v;
        float m2 = v2;
        #pragma unroll
        for (int m = 1; m < 32; m <<= 1) m2 = fminf(m2, __shfl_xor(m2, m));
        unsigned long long bm2 = __ballot(v2 == m2);
        const int wl2 = __ffs((unsigned)(bm2 >> (q * 32))) - 1;
        const int i0 = (int)(((__float_as_uint(m1) & 31u) << 5) | (unsigned)wl);
        const int i1 = (int)(((__float_as_uint(m2) & 31u) << 5) | (unsigned)wl2);
        if (l31 == s) { keep_i0 = i0; keep_i1 = i1; }   // lane s owns slot s
    }

    // ---- per-lane exact fp32 rescore of its own point's 2 candidates ----
    const int rS   = l31 & 15;
    const int prow = (l31 >> 4) * 32 + (rS & 3) + 8 * (rS >> 2) + 4 * q;
    const int p    = pbase + w * 64 + prow;
    const int ia = keep_i0, ib = keep_i1;               // local [0,512)
    const float4* xr = x4 + (size_t)p * 16;
    const float4* ca = c4p + (size_t)(half * 512 + ia) * 16;
    const float4* cb = c4p + (size_t)(half * 512 + ib) * 16;
    float da = 0.f, db = 0.f;
    #pragma unroll
    for (int j = 0; j < 16; ++j) {
        float4 xv = xr[j], av = ca[j], bv = cb[j];
        float4 d1 = make_float4(xv.x-av.x, xv.y-av.y, xv.z-av.z, xv.w-av.w);
        float4 d2 = make_float4(xv.x-bv.x, xv.y-bv.y, xv.z-bv.z, xv.w-bv.w);
        da += dot4(d1, d1);
        db += dot4(d2, d2);
    }
    const bool ta = (da < db) || (da == db && ia < ib);
    const int   bidx = half * 512 + (ta ? ia : ib);
    const float bd   = ta ? da : db;
    // partial scratch in the gather region (overwritten later by merge2)
    float* Pi = out + (size_t)(2 + half * 2) * N_PTS;
    Pi[p]         = (float)bidx;
    Pi[N_PTS + p] = bd;
}

// pick the winning half per point (reads scratch, writes idx+dist outputs)
__launch_bounds__(256)
__global__ void vq_merge1(float* __restrict__ out) {
    const int p = blockIdx.x * 256 + threadIdx.x;
    const float i0 = out[2 * (size_t)N_PTS + p];
    const float d0 = out[3 * (size_t)N_PTS + p];
    const float i1 = out[4 * (size_t)N_PTS + p];
    const float d1 = out[5 * (size_t)N_PTS + p];
    const bool ta = (d0 < d1) || (d0 == d1);   // tie -> half0 (smaller index)
    out[p]         = ta ? i0 : i1;
    out[N_PTS + p] = sqrtf(fmaxf(ta ? d0 : d1, 0.f));
}

// gather quantized_data (overwrites scratch; kernel boundary orders it)
__launch_bounds__(256)
__global__ void vq_merge2(const float* __restrict__ cw, float* __restrict__ out) {
    __shared__ int sidx[256];
    const int tid = threadIdx.x;
    const int base = blockIdx.x * 256;
    sidx[tid] = (int)out[base + tid];
    __syncthreads();
    const float4* c4p = (const float4*)cw;
    float4* od = (float4*)(out + 2 * (size_t)N_PTS) + (size_t)base * 16;
    #pragma unroll
    for (int i = 0; i < 16; ++i) {
        const int g = i * 256 + tid;
        od[g] = c4p[(size_t)sidx[g >> 4] * 16 + (g & 15)];
    }
}

extern "C" void kernel_launch(void* const* d_in, const int* in_sizes, int n_in,
                              void* d_out, int out_size, void* d_ws, size_t ws_size,
                              hipStream_t stream) {
    const float* x  = (const float*)d_in[0];
    const float* cw = (const float*)d_in[1];
    float* out = (float*)d_out;
    unsigned char* ws = (unsigned char*)d_ws;
    vq_prep<<<4, 256, 0, stream>>>(cw, ws);
    vq_main<<<N_PTS / 512 * 2, 512, 0, stream>>>(x, cw, ws, out);
    vq_merge1<<<N_PTS / 256, 256, 0, stream>>>(out);
    vq_merge2<<<N_PTS / 256, 256, 0, stream>>>(cw, out);
}